// Round 7
// baseline (477.063 us; speedup 1.0000x reference)
//
#include <hip/hip_runtime.h>
#include <cstddef>

// Problem constants (match reference): B=32, D=64, T=8192, K=512
#define B_ 32
#define D_ 64
#define T_ 8192
#define K_ 512

// Candidate filter threshold: |approx_score - exact_score| is bounded far
// below 1e-3 (bf16 per-term err <= |x*e|*2^-8, |e|<=1/512, 64 terms,
// Bernstein tail ~e^-36 at 1e-3). Delta = 2e-3 gives >=4x safety margin;
// exact-DAG argmin is provably inside the candidate set.
#define DELTA 2e-3f

typedef __attribute__((ext_vector_type(2))) float v2f;
typedef __attribute__((ext_vector_type(4))) float f32x4;
typedef __attribute__((ext_vector_type(8))) short bf16x8;

// ---------------------------------------------------------------------------
// ROUND-9: two-phase MFMA-filtered argmin. (R8 failed to compile: `#pragma
// clang fp` must open a compound statement; phase-3 loop now wrapped in its
// own brace. No functional change vs R8.)
//
//   R2-R7 evidence: the exact npyv fp32 DAG is VALU-roofline-bound at
//   ~145-180us (v_pk_fma_f32 is HALF-RATE: fp32 peak 157 TF = 1 lane-FMA/
//   SIMD/cyc, so even a fully dictated 46-instr stream costs ~170cyc/k/wave).
//   The only way down is fewer exact evaluations:
//     phase 1: approx scores e2-2*xe for ALL (t,k) via bf16 MFMA
//              (16x16x32) + per-t min.
//     phase 2: re-scan (deterministic recompute), collect candidates with
//              score <= min+DELTA (avg ~1.3 per t).
//     phase 3: exact npyv DAG (bit-identical R0 code) only on candidates;
//              single-candidate t's need NO exact eval (only the index is
//              output, and all other k are provably worse).
//   Fragment-layout safety: A and B d-axes are loaded with the SAME
//   (lane%16, 8*(lane/16)+j) convention -> any k-grouping mis-guess is a
//   matched permutation and cancels in the dot product. C layout is the
//   doc-verified col=lane&15, row=4*(lane>>4)+reg.
// ---------------------------------------------------------------------------

__device__ inline unsigned short f2bf(float f) {  // RNE float->bf16
    unsigned u = __builtin_bit_cast(unsigned, f);
    unsigned r = (u + 0x7fffu + ((u >> 16) & 1u)) >> 16;
    return (unsigned short)r;
}

// ---- prep: exact e2 table (numpy pairwise-8, bit-identical to R0 LDS path)
__global__ void e2_kernel(const float* __restrict__ emb, float* __restrict__ e2) {
#pragma clang fp contract(off)
    int k = blockIdx.x * 256 + threadIdx.x;
    if (k < K_) {
        const float* er = emb + k * D_;
        float r[8];
#pragma unroll
        for (int j = 0; j < 8; ++j) r[j] = er[j] * er[j];
#pragma unroll
        for (int i = 8; i < 64; i += 8) {
#pragma unroll
            for (int j = 0; j < 8; ++j) {
                float p = er[i + j] * er[i + j];
                r[j] = r[j] + p;
            }
        }
        e2[k] = ((r[0] + r[1]) + (r[2] + r[3])) + ((r[4] + r[5]) + (r[6] + r[7]));
    }
}

// ---- prep: emb -> bf16 B-fragments, pre-arranged so phase-1 loads are
// linear uint4 per lane. Layout: bfr[(kt*2+h)*64 + (k%16 + 16*g)][j] holds
// bf16(emb[k][32h+8g+j]) -- B convention n=lane%16, d-chunk=lane/16.
__global__ void bfrag_kernel(const float* __restrict__ emb,
                             unsigned short* __restrict__ bfr) {
    int k = blockIdx.x * 256 + threadIdx.x;
    if (k < K_) {
        int kt = k >> 4, lo = k & 15;
#pragma unroll
        for (int h = 0; h < 2; ++h)
#pragma unroll
            for (int g = 0; g < 4; ++g)
#pragma unroll
                for (int j = 0; j < 8; ++j) {
                    int d = 32 * h + 8 * g + j;
                    bfr[(((size_t)(kt * 2 + h) * 64) + (lo + 16 * g)) * 8 + j] =
                        f2bf(emb[k * D_ + d]);
                }
    }
}

__global__ __launch_bounds__(256) void vq_kernel(const float* __restrict__ x,
                                                 const float* __restrict__ emb,
                                                 const float* __restrict__ e2g,
                                                 const uint4* __restrict__ bfr,
                                                 float* __restrict__ out) {
    __shared__ uint4 sA[4][4][2][64];          // [wave][ttile][dhalf][lane] A-frags
    __shared__ float s_e2[K_];
    __shared__ int s_cnt[256];
    __shared__ unsigned short s_cand[256][8];

    const int tid = threadIdx.x;
    const int w = tid >> 6, l = tid & 63;
    const int lo = l & 15, g = l >> 4;
    const int t = blockIdx.x * 256 + tid;
    const int b = blockIdx.y;
    const float* xp = x + ((size_t)b * D_) * T_ + t;

    for (int kk = tid; kk < K_; kk += 256) s_e2[kk] = e2g[kk];
    s_cnt[tid] = 0;

    // ---- stage 0: load x column, exact x2, emit A-fragments to LDS
    float x2;
    {
        float xv[D_];
#pragma unroll
        for (int d = 0; d < D_; ++d) xv[d] = xp[(size_t)d * T_];
        {
#pragma clang fp contract(off)
            float r[8];
#pragma unroll
            for (int j = 0; j < 8; ++j) r[j] = xv[j] * xv[j];
#pragma unroll
            for (int i = 8; i < 64; i += 8)
#pragma unroll
                for (int j = 0; j < 8; ++j) {
                    float p = xv[i + j] * xv[i + j];
                    r[j] = r[j] + p;
                }
            x2 = ((r[0] + r[1]) + (r[2] + r[3])) + ((r[4] + r[5]) + (r[6] + r[7]));
        }
        // A-frag writer: thread owns row l of its wave's 64-row block:
        // tt=l/16, row-in-tile=l%16; d-chunk (h,g2) -> frag lane (l%16+16*g2).
#pragma unroll
        for (int h = 0; h < 2; ++h)
#pragma unroll
            for (int g2 = 0; g2 < 4; ++g2) {
                int d0 = 32 * h + 8 * g2;
                uint4 pk;
                pk.x = (unsigned)f2bf(xv[d0 + 0]) | ((unsigned)f2bf(xv[d0 + 1]) << 16);
                pk.y = (unsigned)f2bf(xv[d0 + 2]) | ((unsigned)f2bf(xv[d0 + 3]) << 16);
                pk.z = (unsigned)f2bf(xv[d0 + 4]) | ((unsigned)f2bf(xv[d0 + 5]) << 16);
                pk.w = (unsigned)f2bf(xv[d0 + 6]) | ((unsigned)f2bf(xv[d0 + 7]) << 16);
                sA[w][l >> 4][h][lo + 16 * g2] = pk;
            }
    }
    __syncthreads();

    // ---- phase 1 pass A: approx scores, per-t running min
    bf16x8 a[4][2];
#pragma unroll
    for (int tt = 0; tt < 4; ++tt)
#pragma unroll
        for (int h = 0; h < 2; ++h)
            a[tt][h] = __builtin_bit_cast(bf16x8, sA[w][tt][h][l]);

    f32x4 m1[4];
#pragma unroll
    for (int tt = 0; tt < 4; ++tt) m1[tt] = (f32x4){3.4e38f, 3.4e38f, 3.4e38f, 3.4e38f};

    {
        uint4 nb0 = bfr[l], nb1 = bfr[64 + l];
        for (int kt = 0; kt < 32; ++kt) {
            uint4 b0u = nb0, b1u = nb1;
            if (kt < 31) { nb0 = bfr[(kt + 1) * 128 + l]; nb1 = bfr[(kt + 1) * 128 + 64 + l]; }
            bf16x8 b0 = __builtin_bit_cast(bf16x8, b0u);
            bf16x8 b1 = __builtin_bit_cast(bf16x8, b1u);
            float e2v = s_e2[kt * 16 + lo];
            f32x4 c[4];
#pragma unroll
            for (int tt = 0; tt < 4; ++tt) c[tt] = (f32x4){0.f, 0.f, 0.f, 0.f};
#pragma unroll
            for (int tt = 0; tt < 4; ++tt)
                c[tt] = __builtin_amdgcn_mfma_f32_16x16x32_bf16(a[tt][0], b0, c[tt], 0, 0, 0);
#pragma unroll
            for (int tt = 0; tt < 4; ++tt)
                c[tt] = __builtin_amdgcn_mfma_f32_16x16x32_bf16(a[tt][1], b1, c[tt], 0, 0, 0);
#pragma unroll
            for (int tt = 0; tt < 4; ++tt)
#pragma unroll
                for (int r = 0; r < 4; ++r) {
                    float s = fmaf(-2.f, c[tt][r], e2v);
                    m1[tt][r] = fminf(m1[tt][r], s);
                }
        }
    }
    // butterfly min across the 16-lane k-class group (masks <16 never cross t)
#pragma unroll
    for (int m = 1; m <= 8; m <<= 1)
#pragma unroll
        for (int tt = 0; tt < 4; ++tt)
#pragma unroll
            for (int r = 0; r < 4; ++r)
                m1[tt][r] = fminf(m1[tt][r], __shfl_xor(m1[tt][r], m));

    // ---- phase 1 pass B: recompute (deterministic), emit candidates
    {
        uint4 nb0 = bfr[l], nb1 = bfr[64 + l];
        for (int kt = 0; kt < 32; ++kt) {
            uint4 b0u = nb0, b1u = nb1;
            if (kt < 31) { nb0 = bfr[(kt + 1) * 128 + l]; nb1 = bfr[(kt + 1) * 128 + 64 + l]; }
            bf16x8 b0 = __builtin_bit_cast(bf16x8, b0u);
            bf16x8 b1 = __builtin_bit_cast(bf16x8, b1u);
            float e2v = s_e2[kt * 16 + lo];
            f32x4 c[4];
#pragma unroll
            for (int tt = 0; tt < 4; ++tt) c[tt] = (f32x4){0.f, 0.f, 0.f, 0.f};
#pragma unroll
            for (int tt = 0; tt < 4; ++tt)
                c[tt] = __builtin_amdgcn_mfma_f32_16x16x32_bf16(a[tt][0], b0, c[tt], 0, 0, 0);
#pragma unroll
            for (int tt = 0; tt < 4; ++tt)
                c[tt] = __builtin_amdgcn_mfma_f32_16x16x32_bf16(a[tt][1], b1, c[tt], 0, 0, 0);
#pragma unroll
            for (int tt = 0; tt < 4; ++tt)
#pragma unroll
                for (int r = 0; r < 4; ++r) {
                    float s = fmaf(-2.f, c[tt][r], e2v);
                    if (s <= m1[tt][r] + DELTA) {
                        int tl = w * 64 + tt * 16 + g * 4 + r;   // C row->t mapping
                        int idx = atomicAdd(&s_cnt[tl], 1);
                        if (idx < 8) s_cand[tl][idx] = (unsigned short)(kt * 16 + lo);
                    }
                }
        }
    }
    __syncthreads();

    // ---- phase 3: exact npyv DAG only on candidates (bit-identical R0 code)
    v2f xr[D_ / 2];
#pragma unroll
    for (int j = 0; j < D_ / 2; ++j) {
        v2f p;
        p[0] = xp[(size_t)(2 * j) * T_];
        p[1] = xp[(size_t)(2 * j + 1) * T_];
        xr[j] = p;
    }
#define XD(d) (xr[(d) >> 1][(d) & 1])

    int n = s_cnt[tid];
    int bi;
    if (n == 1) {
        bi = s_cand[tid][0];   // provably the exact-DAG argmin; no eval needed
    } else {
        float best = 3.4e38f;
        bi = 0;
        const bool full = (n > 8);         // overflow (astronomically rare)
        const int cnt = full ? K_ : n;
        {
#pragma clang fp contract(off)
            for (int i = 0; i < cnt; ++i) {
                int k = full ? i : (int)s_cand[tid][i];
                const float* er = emb + k * D_;
                v2f acc[8];
#pragma unroll
                for (int j = 0; j < 8; ++j) {
                    int L = 2 * j;
                    v2f ev, z;
                    z[0] = 0.f; z[1] = 0.f;
                    ev[0] = er[48 + L]; ev[1] = er[49 + L];
                    acc[j] = __builtin_elementwise_fma(xr[(48 + L) >> 1], ev, z);
                    ev[0] = er[32 + L]; ev[1] = er[33 + L];
                    acc[j] = __builtin_elementwise_fma(xr[(32 + L) >> 1], ev, acc[j]);
                    ev[0] = er[16 + L]; ev[1] = er[17 + L];
                    acc[j] = __builtin_elementwise_fma(xr[(16 + L) >> 1], ev, acc[j]);
                    ev[0] = er[0 + L];  ev[1] = er[1 + L];
                    acc[j] = __builtin_elementwise_fma(xr[(0 + L) >> 1], ev, acc[j]);
                }
                v2f s8_0 = acc[0] + acc[4];
                v2f s8_1 = acc[1] + acc[5];
                v2f s8_2 = acc[2] + acc[6];
                v2f s8_3 = acc[3] + acc[7];
                v2f s4_0 = s8_0 + s8_2;
                v2f s4_1 = s8_1 + s8_3;
                v2f s2v  = s4_0 + s4_1;
                float xe = s2v[0] + s2v[1];
                float tt2  = fmaf(-2.0f, xe, x2);
                float dist = tt2 + s_e2[k];
                if (dist < best || (dist == best && k < bi)) { best = dist; bi = k; }
            }
        }
    }

    // ---- epilogue: out0 = x + (q - x) elementwise fp32, out1 = q
    const float* q = emb + bi * D_;
    float* o0 = out + ((size_t)b * D_) * T_ + t;
    float* o1 = o0 + (size_t)B_ * D_ * T_;
    {
#pragma clang fp contract(off)
#pragma unroll
        for (int d = 0; d < D_; ++d) {
            float qd = q[d];
            float xd = XD(d);
            float diff = qd - xd;
            o0[(size_t)d * T_] = xd + diff;
            o1[(size_t)d * T_] = qd;
        }
    }
#undef XD
}

// ---------------------------------------------------------------------------
// Fallback: the R0 C++ kernel (verified 377us, absmax==0) if ws is too small.
// ---------------------------------------------------------------------------
__global__ __launch_bounds__(256, 4) void vq_kernel_fb(const float* __restrict__ x,
                                                       const float* __restrict__ emb,
                                                       float* __restrict__ out) {
    __shared__ float s_e2[K_];
    {
#pragma clang fp contract(off)
        for (int k = threadIdx.x; k < K_; k += 256) {
            const float* er = emb + k * D_;
            float r[8];
#pragma unroll
            for (int j = 0; j < 8; ++j) r[j] = er[j] * er[j];
#pragma unroll
            for (int i = 8; i < 64; i += 8) {
#pragma unroll
                for (int j = 0; j < 8; ++j) {
                    float p = er[i + j] * er[i + j];
                    r[j] = r[j] + p;
                }
            }
            s_e2[k] = ((r[0] + r[1]) + (r[2] + r[3])) + ((r[4] + r[5]) + (r[6] + r[7]));
        }
    }
    __syncthreads();

    const int t = blockIdx.x * 256 + threadIdx.x;
    const int b = blockIdx.y;
    const float* xp = x + ((size_t)b * D_) * T_ + t;

    v2f xr[D_ / 2];
#pragma unroll
    for (int j = 0; j < D_ / 2; ++j) {
        v2f p;
        p[0] = xp[(size_t)(2 * j) * T_];
        p[1] = xp[(size_t)(2 * j + 1) * T_];
        xr[j] = p;
    }
#define XD(d) (xr[(d) >> 1][(d) & 1])

    float x2;
    {
#pragma clang fp contract(off)
        float r[8];
#pragma unroll
        for (int j = 0; j < 8; ++j) r[j] = XD(j) * XD(j);
#pragma unroll
        for (int i = 8; i < 64; i += 8) {
#pragma unroll
            for (int j = 0; j < 8; ++j) {
                float p = XD(i + j) * XD(i + j);
                r[j] = r[j] + p;
            }
        }
        x2 = ((r[0] + r[1]) + (r[2] + r[3])) + ((r[4] + r[5]) + (r[6] + r[7]));
    }

    float best = 3.4e38f;
    int bi = 0;
    {
#pragma clang fp contract(off)
        for (int k = 0; k < K_; ++k) {
            const float* er = emb + k * D_;
            v2f acc[8];
#pragma unroll
            for (int j = 0; j < 8; ++j) {
                int L = 2 * j;
                v2f ev, z;
                z[0] = 0.f; z[1] = 0.f;
                ev[0] = er[48 + L]; ev[1] = er[49 + L];
                acc[j] = __builtin_elementwise_fma(xr[(48 + L) >> 1], ev, z);
                ev[0] = er[32 + L]; ev[1] = er[33 + L];
                acc[j] = __builtin_elementwise_fma(xr[(32 + L) >> 1], ev, acc[j]);
                ev[0] = er[16 + L]; ev[1] = er[17 + L];
                acc[j] = __builtin_elementwise_fma(xr[(16 + L) >> 1], ev, acc[j]);
                ev[0] = er[0 + L];  ev[1] = er[1 + L];
                acc[j] = __builtin_elementwise_fma(xr[(0 + L) >> 1], ev, acc[j]);
            }
            v2f s8_0 = acc[0] + acc[4];
            v2f s8_1 = acc[1] + acc[5];
            v2f s8_2 = acc[2] + acc[6];
            v2f s8_3 = acc[3] + acc[7];
            v2f s4_0 = s8_0 + s8_2;
            v2f s4_1 = s8_1 + s8_3;
            v2f s2   = s4_0 + s4_1;
            float xe = s2[0] + s2[1];
            float tt   = fmaf(-2.0f, xe, x2);
            float dist = tt + s_e2[k];
            if (dist < best) { best = dist; bi = k; }
        }
    }

    const float* q = emb + bi * D_;
    float* o0 = out + ((size_t)b * D_) * T_ + t;
    float* o1 = o0 + (size_t)B_ * D_ * T_;
    {
#pragma clang fp contract(off)
#pragma unroll
        for (int d = 0; d < D_; ++d) {
            float qd = q[d];
            float xd = XD(d);
            float diff = qd - xd;
            o0[(size_t)d * T_] = xd + diff;
            o1[(size_t)d * T_] = qd;
        }
    }
#undef XD
}

extern "C" void kernel_launch(void* const* d_in, const int* in_sizes, int n_in,
                              void* d_out, int out_size, void* d_ws, size_t ws_size,
                              hipStream_t stream) {
    const float* x   = (const float*)d_in[0];   // [B, D, T] fp32
    const float* emb = (const float*)d_in[1];   // [K, D] fp32
    float* out = (float*)d_out;                 // [2, B, D, T] fp32

    const size_t e2_bytes = K_ * sizeof(float);                 // 2 KB
    const size_t bfr_bytes = (size_t)K_ * D_ * sizeof(unsigned short);  // 64 KB

    if (d_ws != nullptr && ws_size >= e2_bytes + bfr_bytes) {
        float* e2ws = (float*)d_ws;
        unsigned short* bfrws = (unsigned short*)((char*)d_ws + e2_bytes);
        e2_kernel<<<dim3(2), dim3(256), 0, stream>>>(emb, e2ws);
        bfrag_kernel<<<dim3(2), dim3(256), 0, stream>>>(emb, bfrws);
        vq_kernel<<<dim3(T_ / 256, B_), dim3(256), 0, stream>>>(
            x, emb, e2ws, (const uint4*)bfrws, out);
    } else {
        vq_kernel_fb<<<dim3(T_ / 256, B_), dim3(256), 0, stream>>>(x, emb, out);
    }
}